// Round 9
// baseline (1872.312 us; speedup 1.0000x reference)
//
#include <hip/hip_runtime.h>
#include <hip/hip_bf16.h>
#include <stdint.h>

typedef __bf16 bf16_t;
typedef bf16_t bf16x8 __attribute__((ext_vector_type(8)));
typedef float  f32x4  __attribute__((ext_vector_type(4)));

#define N_FEAT 128
#define BSHIFT 6
#define BROWS  64          // rows per bucket; col must fit 17 bits (N <= 131072)

// ---- detect edge integer width: int64 edges have zero high words ----
__global__ void detect_k(const int* __restrict__ edges, int* __restrict__ flag) {
    int s = 0;
    for (int i = 1; i < 64; i += 2) s |= edges[i];
    *flag = (s == 0) ? 1 : 0;   // 1 => int64 storage (stride 2), 0 => int32
}
__device__ inline int eread(const int* __restrict__ edges, int f, long i) {
    return f ? edges[2 * i] : edges[i];
}

__device__ inline bf16x8 cvt8(const float* __restrict__ p) {
    f32x4 lo = *(const f32x4*)p;
    f32x4 hi = *(const f32x4*)(p + 4);
    bf16x8 r;
    r[0] = (bf16_t)lo[0]; r[1] = (bf16_t)lo[1]; r[2] = (bf16_t)lo[2]; r[3] = (bf16_t)lo[3];
    r[4] = (bf16_t)hi[0]; r[5] = (bf16_t)hi[1]; r[6] = (bf16_t)hi[2]; r[7] = (bf16_t)hi[3];
    return r;
}

// ---- X_hat = X @ W^T : fp32 in -> bf16 frags -> MFMA fp32 acc -> bf16 out --
//   A: lane holds A[row=lane&15][k=(lane>>4)*8+i]
//   B: lane holds B[k=(lane>>4)*8+i][col=lane&15] == W[col][k] (K-contig)
//   D: col=lane&15, row=(lane>>4)*4+reg   [m89/m91]
__global__ __launch_bounds__(64) void gemm_xwt(const float* __restrict__ X,
                                               const float* __restrict__ W,
                                               bf16_t* __restrict__ Xhat) {
    const int lane = threadIdx.x;
    const int m  = lane & 15;
    const int kq = lane >> 4;
    const long r0 = (long)blockIdx.x * 16;

    f32x4 acc[8];
#pragma unroll
    for (int c = 0; c < 8; ++c) acc[c] = (f32x4){0.f, 0.f, 0.f, 0.f};

    const float* xrow = X + (r0 + m) * N_FEAT + kq * 8;
#pragma unroll
    for (int kb = 0; kb < 4; ++kb) {
        bf16x8 a = cvt8(xrow + kb * 32);
#pragma unroll
        for (int c = 0; c < 8; ++c) {
            bf16x8 b = cvt8(W + (c * 16 + m) * N_FEAT + kb * 32 + kq * 8);
            acc[c] = __builtin_amdgcn_mfma_f32_16x16x32_bf16(a, b, acc[c], 0, 0, 0);
        }
    }
#pragma unroll
    for (int c = 0; c < 8; ++c) {
#pragma unroll
        for (int i = 0; i < 4; ++i) {
            long r = r0 + kq * 4 + i;
            Xhat[r * N_FEAT + c * 16 + m] = (bf16_t)acc[c][i];
        }
    }
}

// ---- one edge pass: col-degree (normalization) + row-bucket histogram ----
__global__ void hist_k(const int* __restrict__ edges, const int* __restrict__ flag,
                       int E, int N,
                       int* __restrict__ cnt_col, int* __restrict__ bcnt) {
    const int f = *flag;
    for (long e = (long)blockIdx.x * blockDim.x + threadIdx.x; e < E;
         e += (long)gridDim.x * blockDim.x) {
        int r = eread(edges, f, e);
        int c = eread(edges, f, (long)E + e);
        if ((unsigned)r < (unsigned)N) atomicAdd(&bcnt[r >> BSHIFT], 1);
        if ((unsigned)c < (unsigned)N) atomicAdd(&cnt_col[c], 1);
    }
}

// ---- single-WG exclusive scan over NB bucket counts -> base, cur ----
__global__ __launch_bounds__(256) void scan_k(const int* __restrict__ bcnt, int NB,
                                              int E,
                                              int* __restrict__ bbase,
                                              int* __restrict__ bcur) {
    __shared__ int tsum[256];
    __shared__ int tex[256];
    const int t = threadIdx.x;            // 256 threads x 8 buckets each (NB<=2048)
    int s = 0;
    for (int i = 0; i < 8; ++i) {
        int b = t * 8 + i;
        if (b < NB) { int v = bcnt[b]; s += (v >= 0 && v <= E) ? v : 0; }
    }
    tsum[t] = s;
    __syncthreads();
    if (t == 0) {
        int run = 0;
        for (int i = 0; i < 256; ++i) { tex[i] = run; run += tsum[i]; }
    }
    __syncthreads();
    int run = tex[t];
    for (int i = 0; i < 8; ++i) {
        int b = t * 8 + i;
        if (b < NB) {
            int v = bcnt[b]; v = (v >= 0 && v <= E) ? v : 0;
            bbase[b] = run; bcur[b] = run; run += v;
        }
    }
}

// ---- dinv[n] = rsqrt(col_degree + 1), in place over cnt_col memory ----
__global__ void dinv_k(int* cnt, float* dinv, int N) {   // aliased: no restrict
    int n = blockIdx.x * blockDim.x + threadIdx.x;
    if (n < N) { int d = cnt[n]; dinv[n] = rsqrtf((float)(d + 1)); }
}

// ---- scatter: per-bucket ticket -> DENSE packed writes ((r&63)<<17 | c) ----
__global__ void scatter_pack_k(const int* __restrict__ edges, const int* __restrict__ flag,
                               int E, int N, int* __restrict__ bcur,
                               uint32_t* __restrict__ epack) {
    long e = (long)blockIdx.x * blockDim.x + threadIdx.x;
    if (e >= E) return;
    const int f = *flag;
    int r = eread(edges, f, e);
    int c = eread(edges, f, (long)E + e);
    if ((unsigned)r >= (unsigned)N || (unsigned)c >= (unsigned)N) return;
    int p = atomicAdd(&bcur[r >> BSHIFT], 1);
    if ((unsigned)p < (unsigned)E)          // guard: clean fail, not fault
        epack[p] = ((uint32_t)(r & (BROWS - 1)) << 17) | (uint32_t)c;
}

// ---- gather: one WG per 64-row bucket, 32KB LDS fp32 accumulator ----
// lane j handles feats j and j+64 -> ds_add_f32 at 2 lanes/bank (conflict-free)
__global__ __launch_bounds__(256) void gather_bucket_k(const uint32_t* __restrict__ epack,
                                                       const int* __restrict__ bbase,
                                                       const int* __restrict__ bcnt,
                                                       const float* __restrict__ dinv,
                                                       const bf16_t* __restrict__ Xhat,
                                                       int N, int E,
                                                       float* __restrict__ out) {
    __shared__ float acc[BROWS * N_FEAT];          // 32 KB
    const int b   = blockIdx.x;
    const int tid = threadIdx.x;
    const int r0  = b << BSHIFT;
    const int nr  = min(BROWS, N - r0);

    // init: acc[lr][j] = dinv[r] * Xhat[r][j]  (self-loop; outer dinv at store)
    for (int idx = tid; idx < nr * N_FEAT; idx += 256) {
        int lr = idx >> 7, j = idx & 127;
        int r  = r0 + lr;
        acc[idx] = dinv[r] * (float)Xhat[(long)r * N_FEAT + j];
    }
    __syncthreads();

    // hardened bounds: even corrupted metadata cannot overrun epack
    int ebase = bbase[b];
    int ecnt  = bcnt[b];
    if (ebase < 0) ebase = 0;
    if (ecnt < 0) ecnt = 0;
    if (ebase > E) ebase = E;
    if (ecnt > E - ebase) ecnt = E - ebase;

    const int wave  = tid >> 6;
    const int lane  = tid & 63;
    for (int i = wave; i < ecnt; i += 4) {
        uint32_t pk = epack[ebase + i];
        uint32_t c  = pk & 0x1FFFFu;
        int lr      = (int)(pk >> 17);
        if (c >= (uint32_t)N) continue;            // unwritten-slot guard
        float dc = dinv[c];
        float x0 = (float)Xhat[(long)c * N_FEAT + lane];
        float x1 = (float)Xhat[(long)c * N_FEAT + 64 + lane];
        atomicAdd(&acc[lr * N_FEAT + lane],      dc * x0);
        atomicAdd(&acc[lr * N_FEAT + 64 + lane], dc * x1);
    }
    __syncthreads();

    for (int idx = tid; idx < nr * N_FEAT; idx += 256) {
        int lr = idx >> 7, j = idx & 127;
        int r  = r0 + lr;
        out[(long)r * N_FEAT + j] = dinv[r] * acc[idx];
    }
}

extern "C" void kernel_launch(void* const* d_in, const int* in_sizes, int n_in,
                              void* d_out, int out_size, void* d_ws, size_t ws_size,
                              hipStream_t stream) {
    const float* X = (const float*)d_in[0];
    const float* W = (const float*)d_in[1];
    const int* edges = (const int*)d_in[2];
    const int E = in_sizes[2] / 2;          // 1,600,000
    const int N = in_sizes[0] / N_FEAT;     // 100,000  (<= 131072 for 17-bit pack)
    const int NB = (N + BROWS - 1) >> BSHIFT;   // 1563 buckets

    char* ws = (char*)d_ws;
    int*      flag    = (int*)ws;
    bf16_t*   Xhat    = (bf16_t*)(ws + 16);
    const size_t xhat_b = (size_t)N * N_FEAT * sizeof(bf16_t);  // 25,600,000
    const size_t n4     = (size_t)N * 4;                        //    400,000
    int*      cnt_col = (int*)(ws + 16 + xhat_b);
    int*      bcnt    = (int*)(ws + 16 + xhat_b + n4);
    int*      bbase   = (int*)(ws + 16 + xhat_b + n4 + 8192);
    int*      bcur    = (int*)(ws + 16 + xhat_b + n4 + 16384);
    uint32_t* epack   = (uint32_t*)(ws + 16 + xhat_b + n4 + 24576);
    float*    dinv    = (float*)cnt_col;    // overwritten by dinv_k

    const size_t need = 16 + xhat_b + n4 + 24576 + (size_t)E * 4;  // ~32.4 MB

    if (ws_size < need || NB > 2048) return;   // clean diagnostic, not a fault

    hipMemsetAsync(cnt_col, 0, n4, stream);
    hipMemsetAsync(bcnt, 0, 8192, stream);
    detect_k<<<1, 1, 0, stream>>>(edges, flag);
    gemm_xwt<<<N / 16, 64, 0, stream>>>(X, W, Xhat);
    hist_k<<<2048, 256, 0, stream>>>(edges, flag, E, N, cnt_col, bcnt);
    scan_k<<<1, 256, 0, stream>>>(bcnt, NB, E, bbase, bcur);
    dinv_k<<<(N + 255) / 256, 256, 0, stream>>>(cnt_col, dinv, N);
    scatter_pack_k<<<(E + 255) / 256, 256, 0, stream>>>(edges, flag, E, N, bcur, epack);
    gather_bucket_k<<<NB, 256, 0, stream>>>(epack, bbase, bcnt, dinv, Xhat, N, E, (float*)d_out);
}